// Round 2
// baseline (780.631 us; speedup 1.0000x reference)
//
#include <hip/hip_runtime.h>
#include <hip/hip_bf16.h>

#define D_MODEL 4096
#define D_FF    16384
#define SEQ     1024

typedef __attribute__((ext_vector_type(4))) float          f32x4;
typedef __attribute__((ext_vector_type(4))) float          fvec4;
typedef __attribute__((ext_vector_type(8))) short          bf16x8;
typedef __attribute__((ext_vector_type(4))) unsigned short u16x4;

constexpr int BM = 256, BN = 256, BK = 64;
constexpr int NTHREADS = 512;  // 8 waves: 2 (M) x 4 (N)

// fp32 -> bf16, round-to-nearest-even. Exact for small ints (the int4 path).
__device__ __forceinline__ unsigned short f2bf(float f) {
    unsigned int u = __builtin_bit_cast(unsigned int, f);
    u += 0x7FFFu + ((u >> 16) & 1u);
    return (unsigned short)(u >> 16);
}

// Dtype-agnostic decode of one kernel word. int4 sign-extended to int32 lands
// in {-8..7}; any fp32 encoding of a nonzero value in [-8,8) is bit-disjoint
// from that set (0 decodes to 0 either way). Branchless cmp+cndmask.
__device__ __forceinline__ float decode_kq(unsigned int w) {
    int iv = (int)w;
    return ((unsigned int)(iv + 8) <= 15u) ? (float)iv
                                           : __builtin_bit_cast(float, w);
}

__global__ __launch_bounds__(NTHREADS, 2)
void int4_gemm_kernel(const float* __restrict__ X, const unsigned int* __restrict__ Kq,
                      const float* __restrict__ scale, float* __restrict__ out)
{
    // A tile: [m][k] bf16, row stride 64*2=128B, XOR-swizzled 16B slots.
    // B tile: [n][k] bf16 (transposed during staging), same swizzle.
    __shared__ short A_lds[BM * BK];
    __shared__ short B_lds[BN * BK];

    // XCD grouping: the 4 M-blocks sharing one B-panel get bids {c, c+8, c+16, c+24}
    // -> same XCD under round-robin dispatch; B panel fits that XCD's L2.
    const int bid = blockIdx.x;
    const int bm  = (bid >> 3) & 3;             // 0..3
    const int bn  = (bid & 7) * 8 + (bid >> 5); // 0..63, bijective

    const int tid  = threadIdx.x;
    const int lane = tid & 63;
    const int w    = tid >> 6;
    const int wr   = w >> 2;      // 0..1
    const int wc   = w & 3;       // 0..3
    const int lrow = lane & 15;
    const int lgrp = lane >> 4;

    const int row0 = bm * BM;
    const int col0 = bn * BN;

    f32x4 acc[8][4];
    #pragma unroll
    for (int i = 0; i < 8; ++i)
        #pragma unroll
        for (int j = 0; j < 4; ++j)
            acc[i][j] = (f32x4){0.f, 0.f, 0.f, 0.f};

    char* aB = (char*)A_lds;
    char* bB = (char*)B_lds;

    for (int kt = 0; kt < D_MODEL / BK; ++kt) {
        const int kbase = kt * BK;

        // ---- stage A: 256x64 fp32 -> bf16 LDS [m][k], swizzled ----
        #pragma unroll
        for (int i = 0; i < 8; ++i) {
            int u  = i * NTHREADS + tid;
            int m  = u >> 4;
            int f4 = u & 15;
            const fvec4 v = *reinterpret_cast<const fvec4*>(
                &X[(size_t)(row0 + m) * D_MODEL + kbase + f4 * 4]);
            u16x4 h;
            #pragma unroll
            for (int e = 0; e < 4; ++e) h[e] = f2bf(v[e]);
            int slot16 = f4 >> 1;
            int boff = m * 128 + ((slot16 ^ (m & 7)) * 16) + (f4 & 1) * 8;
            *reinterpret_cast<u16x4*>(aB + boff) = h;
        }

        // ---- stage B: 64x256 kernel words -> bf16 LDS [n][k] (transpose), swizzled ----
        #pragma unroll
        for (int i = 0; i < 4; ++i) {
            int u  = i * NTHREADS + tid;
            int k8 = u >> 8;
            int n  = u & 255;
            const unsigned int* src = &Kq[(size_t)(kbase + k8 * 8) * D_FF + col0 + n];
            unsigned int vv[8];
            #pragma unroll
            for (int j = 0; j < 8; ++j) vv[j] = src[(size_t)j * D_FF];
            bf16x8 h;
            #pragma unroll
            for (int j = 0; j < 8; ++j) h[j] = (short)f2bf(decode_kq(vv[j]));
            int boff = n * 128 + ((k8 ^ (n & 7)) * 16);
            *reinterpret_cast<bf16x8*>(bB + boff) = h;
        }

        __syncthreads();

        // ---- compute: 2 k-slices x 8x4 fragments = 64 MFMA / wave / K-step ----
        #pragma unroll
        for (int ks = 0; ks < 2; ++ks) {
            bf16x8 afrag[8];
            bf16x8 bfrag[4];
            #pragma unroll
            for (int i = 0; i < 8; ++i) {
                int r = wr * 128 + i * 16 + lrow;
                int s = (ks * 4 + lgrp) ^ (r & 7);
                afrag[i] = *reinterpret_cast<const bf16x8*>(aB + r * 128 + s * 16);
            }
            #pragma unroll
            for (int j = 0; j < 4; ++j) {
                int n = wc * 64 + j * 16 + lrow;
                int s = (ks * 4 + lgrp) ^ (n & 7);
                bfrag[j] = *reinterpret_cast<const bf16x8*>(bB + n * 128 + s * 16);
            }
            #pragma unroll
            for (int i = 0; i < 8; ++i)
                #pragma unroll
                for (int j = 0; j < 4; ++j)
                    acc[i][j] = __builtin_amdgcn_mfma_f32_16x16x32_bf16(
                        afrag[i], bfrag[j], acc[i][j], 0, 0, 0);
        }

        __syncthreads();
    }

    // ---- epilogue: per-column 1/scale, store fp32 ----
    // C/D layout (m89-verified): col = lane&15, row = (lane>>4)*4 + reg.
    #pragma unroll
    for (int j = 0; j < 4; ++j) {
        int col = col0 + wc * 64 + j * 16 + lrow;
        float rs = 1.0f / scale[col];
        #pragma unroll
        for (int i = 0; i < 8; ++i) {
            int r0 = row0 + wr * 128 + i * 16 + lgrp * 4;
            #pragma unroll
            for (int r = 0; r < 4; ++r)
                out[(size_t)(r0 + r) * D_FF + col] = acc[i][j][r] * rs;
        }
    }
}

extern "C" void kernel_launch(void* const* d_in, const int* in_sizes, int n_in,
                              void* d_out, int out_size, void* d_ws, size_t ws_size,
                              hipStream_t stream) {
    const float*        X     = (const float*)d_in[0];
    const unsigned int* Kq    = (const unsigned int*)d_in[1];
    const float*        scale = (const float*)d_in[2];
    float*              out   = (float*)d_out;

    dim3 grid((SEQ / BM) * (D_FF / BN));  // 4 * 64 = 256 blocks
    dim3 block(NTHREADS);
    int4_gemm_kernel<<<grid, block, 0, stream>>>(X, Kq, scale, out);
}

// Round 3
// 521.451 us; speedup vs baseline: 1.4970x; 1.4970x over previous
//
#include <hip/hip_runtime.h>
#include <hip/hip_bf16.h>

#define D_MODEL 4096
#define D_FF    16384
#define SEQ     1024

typedef __attribute__((ext_vector_type(4))) float          f32x4;
typedef __attribute__((ext_vector_type(4))) float          fvec4;
typedef __attribute__((ext_vector_type(8))) short          bf16x8;
typedef __attribute__((ext_vector_type(4))) unsigned short u16x4;

constexpr int BM = 256, BN = 256, BK = 64;
constexpr int NTHREADS = 512;          // 8 waves: 2 (M) x 4 (N)
constexpr int NT = D_MODEL / BK;       // 64 K-steps

// fp32 -> bf16, round-to-nearest-even. Exact for small ints (the int4 path).
__device__ __forceinline__ unsigned short f2bf(float f) {
    unsigned int u = __builtin_bit_cast(unsigned int, f);
    u += 0x7FFFu + ((u >> 16) & 1u);
    return (unsigned short)(u >> 16);
}

// Dtype-agnostic decode of one kernel word. int4 sign-extended to int32 lands
// in {-8..7}; any fp32 encoding of a nonzero value in [-8,8) is bit-disjoint
// from that set (0 decodes to 0 either way). Branchless cmp+cndmask.
__device__ __forceinline__ float decode_kq(unsigned int w) {
    int iv = (int)w;
    return ((unsigned int)(iv + 8) <= 15u) ? (float)iv
                                           : __builtin_bit_cast(float, w);
}

__global__ __launch_bounds__(NTHREADS, 2)
void int4_gemm_kernel(const float* __restrict__ X, const unsigned int* __restrict__ Kq,
                      const float* __restrict__ scale, float* __restrict__ out)
{
    // Double-buffered tiles. A: [m][k] bf16 row stride 128B; B: [n][k] bf16
    // (transposed in staging). Both XOR-swizzled on 16B slots (bank-conflict-free,
    // verified: SQ_LDS_BANK_CONFLICT == 0 in round 2).
    __shared__ short A_lds[2][BM * BK];
    __shared__ short B_lds[2][BN * BK];

    // XCD grouping: the 4 M-blocks sharing one B-panel get bids {c,c+8,c+16,c+24}
    // -> same XCD under round-robin dispatch; B panel fits that XCD's L2.
    const int bid = blockIdx.x;
    const int bm  = (bid >> 3) & 3;             // 0..3
    const int bn  = (bid & 7) * 8 + (bid >> 5); // 0..63, bijective

    const int tid  = threadIdx.x;
    const int lane = tid & 63;
    const int w    = tid >> 6;
    const int wr   = w >> 2;      // 0..1
    const int wc   = w & 3;       // 0..3
    const int lrow = lane & 15;
    const int lgrp = lane >> 4;

    const int row0 = bm * BM;
    const int col0 = bn * BN;

    // Per-thread staging-unit coordinates (constant across K-steps).
    const int a_m  = tid >> 4;          // row handled in A-stage chunk (with +32*i)
    const int a_f4 = tid & 15;          // float4 index within the 64-wide k row
    const int b_n  = tid & 255;         // column handled in B-stage chunk
    const int b_k8 = tid >> 8;          // k-octet (with +2*i)

    f32x4 acc[8][4];
    #pragma unroll
    for (int i = 0; i < 8; ++i)
        #pragma unroll
        for (int j = 0; j < 4; ++j)
            acc[i][j] = (f32x4){0.f, 0.f, 0.f, 0.f};

    // Prefetch registers (raw, unconverted). A: 8 x float4. B: 4 x 8 dwords.
    fvec4        aReg[8];
    unsigned int bReg[4][8];

    auto issue_loads = [&](int kt) {
        const int kbase = kt * BK;
        #pragma unroll
        for (int i = 0; i < 8; ++i) {
            int m = a_m + i * 32;
            aReg[i] = *reinterpret_cast<const fvec4*>(
                &X[(size_t)(row0 + m) * D_MODEL + kbase + a_f4 * 4]);
        }
        #pragma unroll
        for (int i = 0; i < 4; ++i) {
            int k8 = b_k8 + i * 2;
            const unsigned int* src =
                &Kq[(size_t)(kbase + k8 * 8) * D_FF + col0 + b_n];
            #pragma unroll
            for (int j = 0; j < 8; ++j) bReg[i][j] = src[(size_t)j * D_FF];
        }
    };

    auto write_lds = [&](int buf) {
        char* aB = (char*)A_lds[buf];
        char* bB = (char*)B_lds[buf];
        #pragma unroll
        for (int i = 0; i < 8; ++i) {
            int m = a_m + i * 32;
            u16x4 h;
            #pragma unroll
            for (int e = 0; e < 4; ++e) h[e] = f2bf(aReg[i][e]);
            int slot16 = a_f4 >> 1;
            int boff = m * 128 + ((slot16 ^ (m & 7)) * 16) + (a_f4 & 1) * 8;
            *reinterpret_cast<u16x4*>(aB + boff) = h;
        }
        #pragma unroll
        for (int i = 0; i < 4; ++i) {
            int k8 = b_k8 + i * 2;
            bf16x8 h;
            #pragma unroll
            for (int j = 0; j < 8; ++j) h[j] = (short)f2bf(decode_kq(bReg[i][j]));
            int boff = b_n * 128 + ((k8 ^ (b_n & 7)) * 16);
            *reinterpret_cast<bf16x8*>(bB + boff) = h;
        }
    };

    issue_loads(0);

    int cur = 0;
    for (int kt = 0; kt < NT; ++kt) {
        // Consume prefetch regs (vmcnt wait via reg-dep), convert, LDS-write.
        write_lds(cur);
        // Re-issue into the same regs for the next tile; stays in flight
        // across the barrier and hides under this step's MFMAs (T14).
        if (kt + 1 < NT) issue_loads(kt + 1);
        __syncthreads();

        const char* aB = (const char*)A_lds[cur];
        const char* bB = (const char*)B_lds[cur];
        #pragma unroll
        for (int ks = 0; ks < 2; ++ks) {
            bf16x8 afrag[8];
            bf16x8 bfrag[4];
            #pragma unroll
            for (int i = 0; i < 8; ++i) {
                int r = wr * 128 + i * 16 + lrow;
                int s = (ks * 4 + lgrp) ^ (r & 7);
                afrag[i] = *reinterpret_cast<const bf16x8*>(aB + r * 128 + s * 16);
            }
            #pragma unroll
            for (int j = 0; j < 4; ++j) {
                int n = wc * 64 + j * 16 + lrow;
                int s = (ks * 4 + lgrp) ^ (n & 7);
                bfrag[j] = *reinterpret_cast<const bf16x8*>(bB + n * 128 + s * 16);
            }
            #pragma unroll
            for (int i = 0; i < 8; ++i)
                #pragma unroll
                for (int j = 0; j < 4; ++j)
                    acc[i][j] = __builtin_amdgcn_mfma_f32_16x16x32_bf16(
                        afrag[i], bfrag[j], acc[i][j], 0, 0, 0);
        }
        cur ^= 1;
        // No trailing barrier needed: buf[cur'] won't be rewritten until the
        // step after next; the single barrier above orders write->read.
    }

    // ---- epilogue: per-column 1/scale, store fp32 ----
    // C/D layout (m89-verified): col = lane&15, row = (lane>>4)*4 + reg.
    #pragma unroll
    for (int j = 0; j < 4; ++j) {
        int col = col0 + wc * 64 + j * 16 + lrow;
        float rs = 1.0f / scale[col];
        #pragma unroll
        for (int i = 0; i < 8; ++i) {
            int r0 = row0 + wr * 128 + i * 16 + lgrp * 4;
            #pragma unroll
            for (int r = 0; r < 4; ++r)
                out[(size_t)(r0 + r) * D_FF + col] = acc[i][j][r] * rs;
        }
    }
}

extern "C" void kernel_launch(void* const* d_in, const int* in_sizes, int n_in,
                              void* d_out, int out_size, void* d_ws, size_t ws_size,
                              hipStream_t stream) {
    const float*        X     = (const float*)d_in[0];
    const unsigned int* Kq    = (const unsigned int*)d_in[1];
    const float*        scale = (const float*)d_in[2];
    float*              out   = (float*)d_out;

    dim3 grid((SEQ / BM) * (D_FF / BN));  // 4 * 64 = 256 blocks
    dim3 block(NTHREADS);
    int4_gemm_kernel<<<grid, block, 0, stream>>>(X, Kq, scale, out);
}

// Round 4
// 463.386 us; speedup vs baseline: 1.6846x; 1.1253x over previous
//
#include <hip/hip_runtime.h>
#include <hip/hip_bf16.h>

#define D_MODEL 4096
#define D_FF    16384
#define SEQ     1024

typedef __attribute__((ext_vector_type(4))) float          fvec4;
typedef __attribute__((ext_vector_type(4))) float          f32x4;
typedef __attribute__((ext_vector_type(4))) int            i32x4;
typedef __attribute__((ext_vector_type(8))) short          bf16x8;
typedef __attribute__((ext_vector_type(4))) unsigned short u16x4;

constexpr int BM = 256, BN = 256, BK = 64;
constexpr int NTHREADS = 512;            // 8 waves: 2 (M) x 4 (N)
constexpr int NT = D_MODEL / BK;         // 64 K-steps
constexpr size_t WS_A_BYTES = 4ull * NT * 32768;  // 8 MiB: [bm:4][kt:64][32KiB tile image]

// fp32 -> bf16 RNE. Exact for small ints.
__device__ __forceinline__ unsigned short f2bf(float f) {
    unsigned int u = __builtin_bit_cast(unsigned int, f);
    u += 0x7FFFu + ((u >> 16) & 1u);
    return (unsigned short)(u >> 16);
}

// bf16 of one kernel word, dtype-agnostic and EXACT either way:
// int4 sign-extended int32 lands in {-8..7} (convert to float, take hi16);
// fp32-encoded int4 value has zero low mantissa bits (hi16 IS the bf16).
__device__ __forceinline__ unsigned short kq_bf16(unsigned int w) {
    int iv = (int)w;
    float fi = (float)iv;
    unsigned int fw = ((unsigned int)(iv + 8) <= 15u)
                        ? __builtin_bit_cast(unsigned int, fi) : w;
    return (unsigned short)(fw >> 16);
}

// ---- pre-kernel: X fp32 -> bf16 once, stored as pre-swizzled A-tile images ----
// Image byte layout == main kernel's LDS A layout, so A staging is a pure copy.
__global__ __launch_bounds__(256)
void preconv_A(const float* __restrict__ X, unsigned short* __restrict__ wsA)
{
    size_t u = (size_t)blockIdx.x * 256 + threadIdx.x;  // one 8B unit (4 bf16)
    size_t g = u * 8;
    int bm    = (int)(g >> 21);          // 2 MiB per bm group
    int r1    = (int)(g & 2097151);
    int kt    = r1 >> 15;                // 32 KiB per K-tile
    int b     = r1 & 32767;
    int m     = b >> 7;                  // row within tile (128 B per row)
    int pslot = (b >> 4) & 7;            // physical 16B slot
    int t     = pslot ^ (m & 7);         // logical k16 slot (inverse of XOR swizzle)
    int o     = (b >> 3) & 1;            // which half of the 16B slot
    int k     = t * 8 + o * 4;
    const fvec4 v = *reinterpret_cast<const fvec4*>(
        &X[(size_t)(bm * 256 + m) * D_MODEL + kt * BK + k]);
    u16x4 h;
    #pragma unroll
    for (int e = 0; e < 4; ++e) h[e] = f2bf(v[e]);
    *reinterpret_cast<u16x4*>((char*)wsA + g) = h;
}

template <bool PRE>
__global__ __launch_bounds__(NTHREADS, 2)
void int4_gemm_kernel(const float* __restrict__ X, const unsigned int* __restrict__ Kq,
                      const float* __restrict__ scale, float* __restrict__ out,
                      const unsigned short* __restrict__ wsA)
{
    // Double-buffered tiles; XOR-swizzled 16B slots (bank-conflict-free, verified r2/r3).
    __shared__ short A_lds[2][BM * BK];
    __shared__ short B_lds[2][BN * BK];

    const int bid = blockIdx.x;
    const int bm  = (bid >> 3) & 3;             // 4 M-blocks sharing a B panel
    const int bn  = (bid & 7) * 8 + (bid >> 5); // land on one XCD (bid%8 round-robin)

    const int tid  = threadIdx.x;
    const int lane = tid & 63;
    const int w    = tid >> 6;
    const int wr   = w >> 2;
    const int wc   = w & 3;
    const int lrow = lane & 15;
    const int lgrp = lane >> 4;

    const int row0 = bm * BM;
    const int col0 = bn * BN;

    const int b_n  = tid & 255;   // B staging: column owned by this thread
    const int b_k8 = tid >> 8;    // k-octet base

    f32x4 acc[8][4];
    #pragma unroll
    for (int i = 0; i < 8; ++i)
        #pragma unroll
        for (int j = 0; j < 4; ++j)
            acc[i][j] = (f32x4){0.f, 0.f, 0.f, 0.f};

    unsigned int bReg[4][8];   // in-flight B tile (raw words)

    auto issueB = [&](int kt) {
        const int kbase = kt * BK;
        #pragma unroll
        for (int i = 0; i < 4; ++i) {
            int k8 = b_k8 + i * 2;
            const unsigned int* src = &Kq[(size_t)(kbase + k8 * 8) * D_FF + col0 + b_n];
            #pragma unroll
            for (int j = 0; j < 8; ++j) bReg[i][j] = src[(size_t)j * D_FF];
        }
    };
    auto convertB = [&](short* Bbuf) {
        char* bB = (char*)Bbuf;
        #pragma unroll
        for (int i = 0; i < 4; ++i) {
            int k8 = b_k8 + i * 2;
            bf16x8 h;
            #pragma unroll
            for (int j = 0; j < 8; ++j) h[j] = (short)kq_bf16(bReg[i][j]);
            int boff = b_n * 128 + ((k8 ^ (b_n & 7)) * 16);
            *reinterpret_cast<bf16x8*>(bB + boff) = h;
        }
    };
    auto stageA = [&](int kt, short* Abuf) {
        if constexpr (PRE) {
            // pure 16B copies: image already bf16 + swizzled
            const char* src = (const char*)wsA + ((size_t)bm << 21) + ((size_t)kt << 15);
            char* dst = (char*)Abuf;
            #pragma unroll
            for (int i = 0; i < 4; ++i) {
                int off = i * 8192 + tid * 16;
                *reinterpret_cast<i32x4*>(dst + off) =
                    *reinterpret_cast<const i32x4*>(src + off);
            }
        } else {
            const int a_m = tid >> 4, a_f4 = tid & 15;
            const int kbase = kt * BK;
            char* aB = (char*)Abuf;
            #pragma unroll
            for (int i = 0; i < 8; ++i) {
                int m = a_m + i * 32;
                const fvec4 v = *reinterpret_cast<const fvec4*>(
                    &X[(size_t)(row0 + m) * D_MODEL + kbase + a_f4 * 4]);
                u16x4 h;
                #pragma unroll
                for (int e = 0; e < 4; ++e) h[e] = f2bf(v[e]);
                int boff = m * 128 + (((a_f4 >> 1) ^ (m & 7)) * 16) + (a_f4 & 1) * 8;
                *reinterpret_cast<u16x4*>(aB + boff) = h;
            }
        }
    };
    auto mfma_step = [&](const short* Abuf, const short* Bbuf) {
        const char* aB = (const char*)Abuf;
        const char* bB = (const char*)Bbuf;
        #pragma unroll
        for (int ks = 0; ks < 2; ++ks) {
            bf16x8 afrag[8];
            bf16x8 bfrag[4];
            #pragma unroll
            for (int i = 0; i < 8; ++i) {
                int r = wr * 128 + i * 16 + lrow;
                int s = (ks * 4 + lgrp) ^ (r & 7);
                afrag[i] = *reinterpret_cast<const bf16x8*>(aB + r * 128 + s * 16);
            }
            #pragma unroll
            for (int j = 0; j < 4; ++j) {
                int n = wc * 64 + j * 16 + lrow;
                int s = (ks * 4 + lgrp) ^ (n & 7);
                bfrag[j] = *reinterpret_cast<const bf16x8*>(bB + n * 128 + s * 16);
            }
            #pragma unroll
            for (int i = 0; i < 8; ++i)
                #pragma unroll
                for (int j = 0; j < 4; ++j)
                    acc[i][j] = __builtin_amdgcn_mfma_f32_16x16x32_bf16(
                        afrag[i], bfrag[j], acc[i][j], 0, 0, 0);
        }
    };
    // Raw barrier: lgkmcnt(0) only — B loads stay IN FLIGHT across it (T4).
    auto tile_barrier = [&]() {
        asm volatile("s_waitcnt lgkmcnt(0)" ::: "memory");
        __builtin_amdgcn_s_barrier();
    };

    // Prologue: buf0 <- tile 0; loads(1) in flight.
    issueB(0);
    stageA(0, A_lds[0]);
    convertB(B_lds[0]);
    issueB(1);
    tile_barrier();

    // Main loop, unrolled x2 so buffer indices are literals (LDS alias disambiguation).
    // Invariant at even kt: buf0 = tile kt ready, bReg = loads(kt+1) in flight.
    for (int kt = 0; kt < NT; kt += 2) {
        // even body: compute buf0, stage kt+1 -> buf1
        if (kt + 1 < NT) { convertB(B_lds[1]); stageA(kt + 1, A_lds[1]); }
        if (kt + 2 < NT) issueB(kt + 2);
        mfma_step(A_lds[0], B_lds[0]);
        tile_barrier();
        // odd body: compute buf1, stage kt+2 -> buf0
        if (kt + 2 < NT) { convertB(B_lds[0]); stageA(kt + 2, A_lds[0]); }
        if (kt + 3 < NT) issueB(kt + 3);
        mfma_step(A_lds[1], B_lds[1]);
        tile_barrier();
    }

    // ---- epilogue: per-column 1/scale, store fp32 ----
    // C/D layout (m89-verified): col = lane&15, row = (lane>>4)*4 + reg.
    #pragma unroll
    for (int j = 0; j < 4; ++j) {
        int col = col0 + wc * 64 + j * 16 + lrow;
        float rs = 1.0f / scale[col];
        #pragma unroll
        for (int i = 0; i < 8; ++i) {
            int r0 = row0 + wr * 128 + i * 16 + lgrp * 4;
            #pragma unroll
            for (int r = 0; r < 4; ++r)
                out[(size_t)(r0 + r) * D_FF + col] = acc[i][j][r] * rs;
        }
    }
}

extern "C" void kernel_launch(void* const* d_in, const int* in_sizes, int n_in,
                              void* d_out, int out_size, void* d_ws, size_t ws_size,
                              hipStream_t stream) {
    const float*        X     = (const float*)d_in[0];
    const unsigned int* Kq    = (const unsigned int*)d_in[1];
    const float*        scale = (const float*)d_in[2];
    float*              out   = (float*)d_out;

    dim3 grid((SEQ / BM) * (D_FF / BN));  // 256 blocks = 1/CU
    dim3 block(NTHREADS);

    if (ws_size >= WS_A_BYTES) {
        unsigned short* wsA = (unsigned short*)d_ws;
        preconv_A<<<dim3((unsigned)(WS_A_BYTES / 8 / 256)), dim3(256), 0, stream>>>(X, wsA);
        int4_gemm_kernel<true><<<grid, block, 0, stream>>>(X, Kq, scale, out, wsA);
    } else {
        int4_gemm_kernel<false><<<grid, block, 0, stream>>>(X, Kq, scale, out, nullptr);
    }
}